// Round 3
// baseline (417.353 us; speedup 1.0000x reference)
//
#include <hip/hip_runtime.h>

// AdaConv2d: out[b,c,h,w] = sum_{ki,kj} xpad[b,c,h+ki-1,w+kj-1] * dk[b,c,ki*3+kj,h,w]
// x [8,64,128,128] f32, dk [8,64,9,128,128] f32, out [8,64,128,128] f32.
// Memory-bound: dk (302 MB, zero reuse) dominates -> nontemporal loads.
// 8 pixels/thread (2x float4): ~28 outstanding loads/thread for latency hiding.
// Wave = 16 lanes/row covering 4 rows: every tap load is 2 KB contiguous/wave.

constexpr int Bc = 8, Cc = 64, Hc = 128, Wc = 128;
constexpr int HW = Hc * Wc;

typedef float f32x4 __attribute__((ext_vector_type(4)));

__global__ __launch_bounds__(256) void adaconv2d_kernel(
    const float* __restrict__ x,
    const float* __restrict__ dk,
    float* __restrict__ out)
{
    // total octs = B*C*H*(W/8) = 1,048,576
    int tid  = blockIdx.x * blockDim.x + threadIdx.x;
    int w0   = (tid & 15) << 3;   // 0,8,...,120
    int rest = tid >> 4;
    int h    = rest & (Hc - 1);
    int bc   = rest >> 7;         // b*C + c

    const float* xp = x + bc * HW;
    const float* kp = dk + (long long)bc * 9 * HW + h * Wc + w0;

    // x rows h-1,h,h+1, columns w0-1 .. w0+8 (zero-padded at borders)
    float xr[3][10];
    #pragma unroll
    for (int r = 0; r < 3; ++r) {
        int hh = h + r - 1;
        if (hh >= 0 && hh < Hc) {
            const float* row = xp + hh * Wc;
            f32x4 m0 = *reinterpret_cast<const f32x4*>(row + w0);
            f32x4 m1 = *reinterpret_cast<const f32x4*>(row + w0 + 4);
            xr[r][1] = m0.x; xr[r][2] = m0.y; xr[r][3] = m0.z; xr[r][4] = m0.w;
            xr[r][5] = m1.x; xr[r][6] = m1.y; xr[r][7] = m1.z; xr[r][8] = m1.w;
            xr[r][0] = (w0 > 0)       ? row[w0 - 1] : 0.f;
            xr[r][9] = (w0 + 8 < Wc)  ? row[w0 + 8] : 0.f;
        } else {
            #pragma unroll
            for (int j = 0; j < 10; ++j) xr[r][j] = 0.f;
        }
    }

    float acc[8];
    #pragma unroll
    for (int j = 0; j < 8; ++j) acc[j] = 0.f;

    #pragma unroll
    for (int r = 0; r < 3; ++r) {
        #pragma unroll
        for (int s = 0; s < 3; ++s) {
            const float* kt = kp + (r * 3 + s) * HW;
            f32x4 k0 = __builtin_nontemporal_load(reinterpret_cast<const f32x4*>(kt));
            f32x4 k1 = __builtin_nontemporal_load(reinterpret_cast<const f32x4*>(kt + 4));
            // out col w0+j uses x col w0+j+s-1 == xr[r][j+s]
            acc[0] += xr[r][s + 0] * k0.x;
            acc[1] += xr[r][s + 1] * k0.y;
            acc[2] += xr[r][s + 2] * k0.z;
            acc[3] += xr[r][s + 3] * k0.w;
            acc[4] += xr[r][s + 4] * k1.x;
            acc[5] += xr[r][s + 5] * k1.y;
            acc[6] += xr[r][s + 6] * k1.z;
            acc[7] += xr[r][s + 7] * k1.w;
        }
    }

    float* op = out + bc * HW + h * Wc + w0;
    f32x4 o0 = { acc[0], acc[1], acc[2], acc[3] };
    f32x4 o1 = { acc[4], acc[5], acc[6], acc[7] };
    __builtin_nontemporal_store(o0, reinterpret_cast<f32x4*>(op));
    __builtin_nontemporal_store(o1, reinterpret_cast<f32x4*>(op + 4));
}

extern "C" void kernel_launch(void* const* d_in, const int* in_sizes, int n_in,
                              void* d_out, int out_size, void* d_ws, size_t ws_size,
                              hipStream_t stream) {
    const float* x  = (const float*)d_in[0];
    const float* dk = (const float*)d_in[1];
    float* out      = (float*)d_out;

    const int total_octs = Bc * Cc * Hc * (Wc / 8); // 1,048,576
    const int block = 256;
    const int grid  = total_octs / block;           // 4096
    adaconv2d_kernel<<<grid, block, 0, stream>>>(x, dk, out);
}